// Round 4
// baseline (166165.112 us; speedup 1.0000x reference)
//
#include <hip/hip_runtime.h>
#include <cmath>

#define DD 1024
#define TT 200
#define NWG 256
#define THR 512

__device__ __forceinline__ float eluf(float x) { return x > 0.f ? x : expm1f(x); }

// ---- system-scope (sc0 sc1) accessors: bypass L1 AND L2, coherent at MALL.
// Unlike round 2's agent-scope (sc1-only) ops, system scope must bypass the
// per-CU L1 (host-coherent fine-grain traffic requires it architecturally).
#define SLOADQ(p) __hip_atomic_load((const unsigned long long*)(p), \
                                    __ATOMIC_RELAXED, __HIP_MEMORY_SCOPE_SYSTEM)
#define SSTOREF(p, v) __hip_atomic_store((unsigned*)(p), __float_as_uint(v), \
                                         __ATOMIC_RELAXED, __HIP_MEMORY_SCOPE_SYSTEM)

// ---------------- 1024x1024 transpose: dst[k][n] = src[n][k] ----------------
__global__ __launch_bounds__(256) void transpose_k(const float* __restrict__ src,
                                                   float* __restrict__ dst) {
  __shared__ float tile[32][33];
  const int bx = blockIdx.x << 5;
  const int by = blockIdx.y << 5;
  const int tx = threadIdx.x & 31;
  const int ty = threadIdx.x >> 5;
#pragma unroll
  for (int i = 0; i < 4; ++i) {
    int r = ty + (i << 3);
    tile[r][tx] = src[(size_t)(bx + r) * DD + by + tx];
  }
  __syncthreads();
#pragma unroll
  for (int i = 0; i < 4; ++i) {
    int r = ty + (i << 3);
    dst[(size_t)(by + r) * DD + bx + tx] = tile[tx][r];
  }
}

// ---------------- phase 0: wxT[b][n][t] = sum_k x[b][k][t]*Win[n][k] + bin[n]
__global__ __launch_bounds__(256) void wx_kernel(const float* __restrict__ x,
                                                 const float* __restrict__ Win,
                                                 const float* __restrict__ bin,
                                                 float* __restrict__ wxT) {
  const int gw = (blockIdx.x << 2) | (threadIdx.x >> 6);
  const int lane = threadIdx.x & 63;
  const int noct = gw & 127;
  const int tt = (gw >> 7) & 3;
  const int b = gw >> 9;
  const int n0 = noct << 3;
  const int t = (tt << 6) + lane;
  const int tl = t < TT ? t : (TT - 1);
  const float* xp = x + (size_t)b * DD * TT + tl;
  float acc[8];
#pragma unroll
  for (int j = 0; j < 8; ++j) acc[j] = 0.f;
  for (int k = 0; k < DD; k += 4) {
    float x0 = xp[(size_t)(k + 0) * TT];
    float x1 = xp[(size_t)(k + 1) * TT];
    float x2 = xp[(size_t)(k + 2) * TT];
    float x3 = xp[(size_t)(k + 3) * TT];
#pragma unroll
    for (int j = 0; j < 8; ++j) {
      const float4 w = *(const float4*)(Win + (size_t)(n0 + j) * DD + k);
      acc[j] = fmaf(x0, w.x, fmaf(x1, w.y, fmaf(x2, w.z, fmaf(x3, w.w, acc[j]))));
    }
  }
  if (t < TT) {
#pragma unroll
    for (int j = 0; j < 8; ++j)
      wxT[((size_t)b * DD + n0 + j) * TT + t] = acc[j] + bin[n0 + j];
  }
}

// ---------------- device-wide barrier: monotonic counter, NO cache inv ------
// Per-thread s_waitcnt vmcnt(0) + s_barrier guarantees every thread's system-
// scope stores are committed at the coherence point before thread 0 arrives.
// No reset, no release/acquire: consumers read data with system-scope loads
// that bypass L1/L2, so there is nothing stale to invalidate.
__device__ __forceinline__ void grid_barrier(unsigned* cnt, unsigned target) {
  asm volatile("s_waitcnt vmcnt(0)" ::: "memory");
  __syncthreads();
  if (threadIdx.x == 0) {
    __hip_atomic_fetch_add(cnt, 1u, __ATOMIC_RELAXED, __HIP_MEMORY_SCOPE_SYSTEM);
    while (__hip_atomic_load(cnt, __ATOMIC_RELAXED, __HIP_MEMORY_SCOPE_SYSTEM) < target)
      __builtin_amdgcn_s_sleep(1);
  }
  __syncthreads();
}

// ---------------- one GEMM stage: out[b0+r][n] = sum_k in[b0+r][k]*Wt[k][n]
// WG: 512 thr = 8 waves. Tile 8 b-rows x 32 n-cols. Wave = k-eighth (128).
// Weights: plain cached loads (L2-resident forever now), 16-deep dbl-buffer.
// Activations: staged via system-scope 8B loads (MALL-coherent).
__device__ __forceinline__ float stage_gemm(const float* __restrict__ Wt,
                                            const float* __restrict__ inrows,
                                            float* __restrict__ in_s,
                                            float* __restrict__ red,
                                            int tid, int k0, int nn, int bg) {
  {  // stage 8 rows (32 KB = 4096 qwords) into LDS; 8 independent sysloads
    const unsigned long long* __restrict__ q = (const unsigned long long*)inrows;
    unsigned long long u0 = SLOADQ(q + tid);
    unsigned long long u1 = SLOADQ(q + tid + 512);
    unsigned long long u2 = SLOADQ(q + tid + 1024);
    unsigned long long u3 = SLOADQ(q + tid + 1536);
    unsigned long long u4 = SLOADQ(q + tid + 2048);
    unsigned long long u5 = SLOADQ(q + tid + 2560);
    unsigned long long u6 = SLOADQ(q + tid + 3072);
    unsigned long long u7 = SLOADQ(q + tid + 3584);
    unsigned long long* qs = (unsigned long long*)in_s;
    qs[tid] = u0;
    qs[tid + 512] = u1;
    qs[tid + 1024] = u2;
    qs[tid + 1536] = u3;
    qs[tid + 2048] = u4;
    qs[tid + 2560] = u5;
    qs[tid + 3072] = u6;
    qs[tid + 3584] = u7;
  }
  __syncthreads();

  const float* wp = Wt + (size_t)k0 * DD + nn;  // lane-coalesced over n, L2-hot
  const float* isp = in_s + (bg << 12) + k0;
  float acc[4];
#pragma unroll
  for (int j = 0; j < 4; ++j) acc[j] = 0.f;
  float wa[16], wb[16];
#pragma unroll
  for (int j = 0; j < 16; ++j) wa[j] = wp[j * DD];

#pragma unroll
  for (int kk = 0; kk < 128; kk += 32) {
#pragma unroll
    for (int j = 0; j < 16; ++j) wb[j] = wp[((kk + 16 + j) & 127) * DD];
#pragma unroll
    for (int rr = 0; rr < 4; ++rr) {
      const float* ip = isp + (rr << 10) + kk;
      const float4 a = *(const float4*)(ip);       // LDS broadcast reads
      const float4 b = *(const float4*)(ip + 4);
      const float4 c = *(const float4*)(ip + 8);
      const float4 d = *(const float4*)(ip + 12);
      acc[rr] = fmaf(a.x, wa[0], fmaf(a.y, wa[1], fmaf(a.z, wa[2], fmaf(a.w, wa[3], acc[rr]))));
      acc[rr] = fmaf(b.x, wa[4], fmaf(b.y, wa[5], fmaf(b.z, wa[6], fmaf(b.w, wa[7], acc[rr]))));
      acc[rr] = fmaf(c.x, wa[8], fmaf(c.y, wa[9], fmaf(c.z, wa[10], fmaf(c.w, wa[11], acc[rr]))));
      acc[rr] = fmaf(d.x, wa[12], fmaf(d.y, wa[13], fmaf(d.z, wa[14], fmaf(d.w, wa[15], acc[rr]))));
    }
#pragma unroll
    for (int j = 0; j < 16; ++j) wa[j] = wp[((kk + 32 + j) & 127) * DD];  // wrap: dead, in-bounds
#pragma unroll
    for (int rr = 0; rr < 4; ++rr) {
      const float* ip = isp + (rr << 10) + kk + 16;
      const float4 a = *(const float4*)(ip);
      const float4 b = *(const float4*)(ip + 4);
      const float4 c = *(const float4*)(ip + 8);
      const float4 d = *(const float4*)(ip + 12);
      acc[rr] = fmaf(a.x, wb[0], fmaf(a.y, wb[1], fmaf(a.z, wb[2], fmaf(a.w, wb[3], acc[rr]))));
      acc[rr] = fmaf(b.x, wb[4], fmaf(b.y, wb[5], fmaf(b.z, wb[6], fmaf(b.w, wb[7], acc[rr]))));
      acc[rr] = fmaf(c.x, wb[8], fmaf(c.y, wb[9], fmaf(c.z, wb[10], fmaf(c.w, wb[11], acc[rr]))));
      acc[rr] = fmaf(d.x, wb[12], fmaf(d.y, wb[13], fmaf(d.z, wb[14], fmaf(d.w, wb[15], acc[rr]))));
    }
  }

  // cross-wave K reduction through LDS
  const int ob = ((tid >> 6) << 8) + (bg << 7) + (nn & 31);
  red[ob] = acc[0];
  red[ob + 32] = acc[1];
  red[ob + 64] = acc[2];
  red[ob + 96] = acc[3];
  __syncthreads();
  float v = 0.f;
  if (tid < 256) {
#pragma unroll
    for (int w = 0; w < 8; ++w) v += red[(w << 8) + tid];
  }
  return v;
}

// ---------------- the whole sequential scan, one cooperative kernel --------
__global__ void __launch_bounds__(THR, 1) rnn_kernel(
    const float* __restrict__ WtH, const float* __restrict__ Wt2,
    const float* __restrict__ Wt3, const float* __restrict__ WtO,
    const float* __restrict__ bh_, const float* __restrict__ b2_,
    const float* __restrict__ b3_, const float* __restrict__ bo_,
    const float* __restrict__ etas_, const float* __restrict__ wxT,
    float* __restrict__ sbuf, float* __restrict__ F1b, float* __restrict__ Gb,
    float* __restrict__ hb, float* __restrict__ outp,
    unsigned* __restrict__ bar) {
  __shared__ float in_s[8192];  // 32 KB
  __shared__ float red[2048];   // 8 KB
  const int tid = threadIdx.x;
  const int lane = tid & 63;
  const int ntile = blockIdx.x & 31;  // blk%8 -> XCD: 2 MB weight slice stays in 4 MB L2
  const int btile = blockIdx.x >> 5;
  const int n0 = ntile << 5;
  const int b0 = btile << 3;
  const int nl = lane & 31;
  const int bg = lane >> 5;
  const int nn = n0 + nl;
  const int k0 = (tid >> 6) << 7;  // wave's 128-k slice

  const bool owner = tid < 256;
  const int orow = (tid & 255) >> 5;
  const int ocol = tid & 31;
  const size_t o = (size_t)(b0 + orow) * DD + (n0 + ocol);

  const float bh = bh_[n0 + ocol], bb2 = b2_[n0 + ocol];
  const float bb3 = b3_[n0 + ocol], bo = bo_[n0 + ocol];
  float eta[5];
#pragma unroll
  for (int i = 0; i < 5; ++i) eta[i] = etas_[i];

  const float* in_sb = sbuf + (size_t)b0 * DD;
  const float* in_F = F1b + (size_t)b0 * DD;
  const float* in_G = Gb + (size_t)b0 * DD;
  const float* in_h = hb + (size_t)b0 * DD;
  const float* wxp = wxT + o * TT;

  float h = 0.f, h0 = 0.f;  // private h-element (owner threads only)
  unsigned tgt = 0;
  for (int t = 0; t < TT; ++t) {
    for (int it = 0; it < 5; ++it) {
      if (it == 0 && t > 0) {
        // output GEMM for previous step shares this barrier window with stage A
        float v = stage_gemm(WtO, in_h, in_s, red, tid, k0, nn, bg);
        if (owner) outp[o * TT + (t - 1)] = v + bo;
      }
      // stage A: F1 = elu((h+h0)@Whid^T + bh + wx)
      float v = stage_gemm(WtH, in_sb, in_s, red, tid, k0, nn, bg);
      if (owner) SSTOREF(F1b + o, eluf(v + bh + wxp[t]));
      tgt += NWG;
      grid_barrier(bar, tgt);
      // stage B: G = elu(F1@W2^T + b2)
      v = stage_gemm(Wt2, in_F, in_s, red, tid, k0, nn, bg);
      if (owner) SSTOREF(Gb + o, eluf(v + bb2));
      tgt += NWG;
      grid_barrier(bar, tgt);
      // stage C: Fn = elu(G@W3^T + b3); h += eta*(Fn - h - h0)
      v = stage_gemm(Wt3, in_G, in_s, red, tid, k0, nn, bg);
      if (owner) {
        float fn = eluf(v + bb3);
        float e = eta[it];
        h += e * (fn - h - h0);
        if (it == 4) {  // step transition: h0 <- h_t, s <- 2*h_t
          h0 = h;
          SSTOREF(sbuf + o, 2.f * h);
          SSTOREF(hb + o, h);  // consumed by next window's output GEMM
        } else {
          SSTOREF(sbuf + o, h + h0);
        }
      }
      tgt += NWG;
      grid_barrier(bar, tgt);
    }
  }
  float v = stage_gemm(WtO, in_h, in_s, red, tid, k0, nn, bg);
  if (owner) outp[o * TT + (TT - 1)] = v + bo;
}

extern "C" void kernel_launch(void* const* d_in, const int* in_sizes, int n_in,
                              void* d_out, int out_size, void* d_ws, size_t ws_size,
                              hipStream_t stream) {
  const float* x = (const float*)d_in[0];
  const float* Win = (const float*)d_in[1];
  const float* bin = (const float*)d_in[2];
  const float* Whid = (const float*)d_in[3];
  const float* bhid = (const float*)d_in[4];
  const float* W2 = (const float*)d_in[5];
  const float* b2 = (const float*)d_in[6];
  const float* W3 = (const float*)d_in[7];
  const float* b3 = (const float*)d_in[8];
  const float* Wout = (const float*)d_in[9];
  const float* bout = (const float*)d_in[10];
  const float* etas = (const float*)d_in[11];
  float* out = (float*)d_out;

  char* ws = (char*)d_ws;
  float* wxT = (float*)(ws);                   // 52.4 MB  [B][D][T]
  float* WtH = (float*)(ws + 52428800);        // 4 MB each, k-major
  float* Wt2 = (float*)(ws + 56623104);
  float* Wt3 = (float*)(ws + 60817408);
  float* WtO = (float*)(ws + 65011712);
  float* sbuf = (float*)(ws + 69206016);       // 256 KB each
  float* F1b = (float*)(ws + 69468160);
  float* Gb = (float*)(ws + 69730304);
  float* hb = (float*)(ws + 69992448);
  unsigned* bar = (unsigned*)(ws + 70516736);  // monotonic arrival counter

  hipMemsetAsync(sbuf, 0, 262144, stream);
  hipMemsetAsync(bar, 0, 256, stream);

  dim3 tb(256);
  dim3 tg(32, 32);
  hipLaunchKernelGGL(transpose_k, tg, tb, 0, stream, Whid, WtH);
  hipLaunchKernelGGL(transpose_k, tg, tb, 0, stream, W2, Wt2);
  hipLaunchKernelGGL(transpose_k, tg, tb, 0, stream, W3, Wt3);
  hipLaunchKernelGGL(transpose_k, tg, tb, 0, stream, Wout, WtO);
  hipLaunchKernelGGL(wx_kernel, dim3(8192), tb, 0, stream, x, Win, bin, wxT);

  void* args[] = {&WtH, &Wt2, &Wt3, &WtO, &bhid, &b2, &b3, &bout, &etas,
                  &wxT, &sbuf, &F1b, &Gb, &hb, &out, &bar};
  hipLaunchCooperativeKernel((void*)rnn_kernel, dim3(NWG), dim3(THR), args, 0, stream);
}